// Round 4
// baseline (28000.269 us; speedup 1.0000x reference)
//
#include <hip/hip_runtime.h>
#include <hip/hip_bf16.h>
#include <math.h>
#include <stdint.h>

// HolomorphicEqProp: B=4096, D_IN=H=1024, D_OUT=256, steps=30.
// Round-4: persistent RNN kernel with NO global_load_lds (bisecting the
// R2/R3 failures): Wr staged via dwordx4 loads -> regs -> ds_write_b128,
// double-buffered, one barrier per stage. All index math identical to R3.
// Setup pipeline (spec-norm, cvt, xproj GEMM, step0) is the validated R1 code.

#define EPSF 1e-12f

typedef short bf16x8 __attribute__((ext_vector_type(8)));
typedef float f32x4 __attribute__((ext_vector_type(4)));

struct Mods { float m[32]; };

__device__ __forceinline__ unsigned short f2bf(float f) {
  union { float f; unsigned u; } v; v.f = f;
  unsigned r = v.u + 0x7FFFu + ((v.u >> 16) & 1u);  // RNE
  return (unsigned short)(r >> 16);
}

// async global->LDS (used only in the validated gemm_bt0)
__device__ __forceinline__ void async16(const void* g, void* l) {
  __builtin_amdgcn_global_load_lds(
      (__attribute__((address_space(1))) void*)(uintptr_t)(g),
      (__attribute__((address_space(3))) void*)(unsigned)(uintptr_t)(l),
      16, 0, 0);
}

__device__ __forceinline__ float block_reduce_sum(float x) {
#pragma unroll
  for (int o = 32; o > 0; o >>= 1) x += __shfl_down(x, o, 64);
  __shared__ float sm[8];
  int lane = threadIdx.x & 63, w = threadIdx.x >> 6;
  if (lane == 0) sm[w] = x;
  __syncthreads();
  float t = 0.f;
  if (threadIdx.x == 0) {
    int nw = (int)(blockDim.x >> 6);
    for (int i = 0; i < nw; ++i) t += sm[i];
  }
  return t;
}

// ---------------- spectral-norm setup (fp32, exact; validated R1) ----------

__global__ void spec_col_partial(const float* __restrict__ W, const float* __restrict__ u,
                                 float* __restrict__ v, int M, int N, int rowsPerBlock) {
  int j = blockIdx.x * blockDim.x + threadIdx.x;
  int i0 = blockIdx.y * rowsPerBlock;
  float acc = 0.f;
  for (int i = i0; i < i0 + rowsPerBlock; ++i)
    acc += W[(size_t)i * N + j] * u[i];
  atomicAdd(&v[j], acc);
}

__global__ void vec_norm2(const float* __restrict__ v, float* __restrict__ out, int n) {
  float acc = 0.f;
  for (int i = threadIdx.x; i < n; i += blockDim.x) { float x = v[i]; acc += x * x; }
  float t = block_reduce_sum(acc);
  if (threadIdx.x == 0) *out = t;
}

__global__ void spec_row_sq(const float* __restrict__ W, const float* __restrict__ v,
                            float* __restrict__ usq, int N) {
  int i = blockIdx.x;
  float acc = 0.f;
  for (int j = threadIdx.x; j < N; j += blockDim.x)
    acc += W[(size_t)i * N + j] * v[j];
  float r = block_reduce_sum(acc);
  if (threadIdx.x == 0) atomicAdd(usq, r * r);
}

__global__ void spec_finalize(float* S) {
  int m = threadIdx.x;
  if (m < 3) {
    float nv = sqrtf(S[m]);
    float inv = 1.f / (nv + EPSF);
    float u2sq = S[3 + m] * inv * inv;
    float nu = sqrtf(u2sq);
    float sigma = u2sq / (nu + EPSF);
    S[6 + m] = 1.f / sigma;
  }
  if (m == 3) S[9] = 1.0f;
}

__global__ void cvt_scaled(const float4* __restrict__ W, const float* __restrict__ sp,
                           ushort4* __restrict__ o, int n4) {
  float s = *sp;
  for (int i = blockIdx.x * blockDim.x + threadIdx.x; i < n4; i += gridDim.x * blockDim.x) {
    float4 w = W[i];
    ushort4 r;
    r.x = f2bf(w.x * s); r.y = f2bf(w.y * s); r.z = f2bf(w.z * s); r.w = f2bf(w.w * s);
    o[i] = r;
  }
}

// h1 = tanh(xproj + b_rec*1)  (validated R1)
__global__ void step0k(const float4* __restrict__ xp, const float4* __restrict__ br,
                       ushort4* __restrict__ h, float mod, int n4, int colmask4) {
  for (int i = blockIdx.x * blockDim.x + threadIdx.x; i < n4; i += gridDim.x * blockDim.x) {
    float4 x = xp[i];
    float4 b = br[i & colmask4];
    ushort4 r;
    r.x = f2bf(tanhf(x.x + b.x * mod));
    r.y = f2bf(tanhf(x.y + b.y * mod));
    r.z = f2bf(tanhf(x.z + b.z * mod));
    r.w = f2bf(tanhf(x.w + b.w * mod));
    h[i] = r;
  }
}

// C = A[M,K] . B[N,K]^T + bias[n], fp32 out (validated R1)
__global__ __launch_bounds__(256) void gemm_bt0(
    const unsigned short* __restrict__ A, const unsigned short* __restrict__ B,
    const float* __restrict__ bias, float* __restrict__ outF,
    int M, int N, int K) {
  constexpr int BM = 128, BN = 128, BK = 32;
  __shared__ __align__(16) unsigned short As[BM * BK];
  __shared__ __align__(16) unsigned short Bs[BN * BK];
  const int tid = threadIdx.x;
  const int wave = tid >> 6, lane = tid & 63;
  const int m0 = blockIdx.x * BM, n0 = blockIdx.y * BN;
  const int wm = (wave >> 1) * 64, wn = (wave & 1) * 64;
  const int lrow = lane & 15, quad = lane >> 4;

  f32x4 acc[4][4] = {};

  for (int k0 = 0; k0 < K; k0 += BK) {
#pragma unroll
    for (int inst = 0; inst < 2; ++inst) {
      int e = inst * 2048 + tid * 8;
      int r = e >> 5, c = e & 31;
      async16(&A[(size_t)(m0 + r) * K + k0 + c], &As[e]);
      async16(&B[(size_t)(n0 + r) * K + k0 + c], &Bs[e]);
    }
    __syncthreads();

    bf16x8 af[4], bfr[4];
#pragma unroll
    for (int i = 0; i < 4; ++i) {
      af[i]  = *(const bf16x8*)&As[(wm + i * 16 + lrow) * BK + quad * 8];
      bfr[i] = *(const bf16x8*)&Bs[(wn + i * 16 + lrow) * BK + quad * 8];
    }
#pragma unroll
    for (int i = 0; i < 4; ++i)
#pragma unroll
      for (int j = 0; j < 4; ++j)
        acc[i][j] = __builtin_amdgcn_mfma_f32_16x16x32_bf16(af[i], bfr[j], acc[i][j], 0, 0, 0);
    __syncthreads();
  }

#pragma unroll
  for (int i = 0; i < 4; ++i)
#pragma unroll
    for (int j = 0; j < 4; ++j) {
      int col = n0 + wn + j * 16 + lrow;
      float bv = bias[col];
#pragma unroll
      for (int r = 0; r < 4; ++r) {
        int row = m0 + wm + i * 16 + quad * 4 + r;
        outF[(size_t)row * N + col] = acc[i][j][r] + bv;
      }
    }
}

// ---------------- persistent RNN: steps 1..29 + output GEMM ----------------
// 256 blocks x 512 threads (8 waves), 16 batch rows per block.
// Staging: per stage s (64/step), Wr rows [(s&1)*512, +512), k [(s>>1)*32,+32)
// -> regs (4 x dwordx4 per thread) -> ds_write_b128 into Bs[stage parity].
// Double-buffered, one barrier per stage. NO global_load_lds here.
__global__ __launch_bounds__(512) void rnn_persist(
    const unsigned short* __restrict__ h1,   // [4096][1024] bf16
    const float* __restrict__ xproj,         // [4096][1024] f32
    const unsigned short* __restrict__ Wr,   // [1024][1024] bf16
    const unsigned short* __restrict__ Wo,   // [256][1024] bf16
    const float* __restrict__ b_rec,
    const float* __restrict__ b_out,
    float* __restrict__ out,                 // [4096][256] f32
    Mods mods) {
  __shared__ __align__(16) unsigned short Bs[2][16384];  // 2 x (512 rows x 32 k)
  __shared__ __align__(16) unsigned short hk[16 * 1032];

  const int tid = threadIdx.x;
  const int w = tid >> 6, lane = tid & 63;
  const int lrow = lane & 15, quad = lane >> 4;
  const int m0 = blockIdx.x * 16;
  const int nb = tid >> 2;         // staging row base (within 512-row half)
  const int ko = (tid & 3) * 8;    // staging k offset (elements)

  // xproj tile -> registers (C-layout), biases
  float xpr[8][4];
  float brec[8];
#pragma unroll
  for (int h = 0; h < 2; ++h)
#pragma unroll
    for (int f = 0; f < 4; ++f) {
      int col = h * 512 + w * 64 + f * 16 + lrow;
      brec[h * 4 + f] = b_rec[col];
#pragma unroll
      for (int r = 0; r < 4; ++r)
        xpr[h * 4 + f][r] = xproj[(size_t)(m0 + quad * 4 + r) * 1024 + col];
    }
  float bout[2];
#pragma unroll
  for (int f = 0; f < 2; ++f) bout[f] = b_out[w * 32 + f * 16 + lrow];

  // h1 tile -> hk (row-major, stride 1032)
  {
    int row = w * 2 + (lane >> 5);
    int cb = (lane & 31) * 8;
#pragma unroll
    for (int it = 0; it < 4; ++it) {
      int col = cb + it * 256;
      *(bf16x8*)&hk[row * 1032 + col] =
          *(const bf16x8*)&h1[(size_t)(m0 + row) * 1024 + col];
    }
  }

  // stage 0 (half0, chunk0) -> regs -> Bs[0]
  bf16x8 stg[4];
#pragma unroll
  for (int r = 0; r < 4; ++r)
    stg[r] = *(const bf16x8*)&Wr[(size_t)(nb + r * 128) * 1024 + ko];
#pragma unroll
  for (int r = 0; r < 4; ++r)
    *(bf16x8*)&Bs[0][tid * 8 + r * 4096] = stg[r];

  // ---- steps t = 1..29 ----
#pragma unroll 1
  for (int t = 1; t < 30; ++t) {
    const float mod = mods.m[t];
    f32x4 acc[8] = {};
#pragma unroll 1
    for (int s = 0; s < 64; ++s) {
      __syncthreads();  // publish Bs[s&1]; all reads of Bs[(s+1)&1] done
      int nld = 4;
      if (s < 63) {
        int ns = s + 1;
        const unsigned short* src =
            Wr + (size_t)((ns & 1) * 512 + nb) * 1024 + (ns >> 1) * 32 + ko;
#pragma unroll
        for (int r = 0; r < 4; ++r)
          stg[r] = *(const bf16x8*)(src + (size_t)r * 131072);
      } else if (t < 29) {
        const unsigned short* src = Wr + (size_t)nb * 1024 + ko;
#pragma unroll
        for (int r = 0; r < 4; ++r)
          stg[r] = *(const bf16x8*)(src + (size_t)r * 131072);
      } else {
        const unsigned short* src = Wo + (size_t)nb * 1024 + ko;
#pragma unroll
        for (int r = 0; r < 2; ++r)
          stg[r] = *(const bf16x8*)(src + (size_t)r * 131072);
        nld = 2;
      }
      const int half = s & 1, chunk = s >> 1;
      bf16x8 a = *(const bf16x8*)&hk[lrow * 1032 + chunk * 32 + quad * 8];
      const unsigned short* bs = Bs[half];
#pragma unroll
      for (int f = 0; f < 4; ++f) {
        bf16x8 b = *(const bf16x8*)&bs[(w * 64 + f * 16 + lrow) * 32 + quad * 8];
        acc[half * 4 + f] =
            __builtin_amdgcn_mfma_f32_16x16x32_bf16(a, b, acc[half * 4 + f], 0, 0, 0);
      }
      unsigned short* dst = &Bs[(s + 1) & 1][tid * 8];
      for (int r = 0; r < nld; ++r)
        *(bf16x8*)(dst + r * 4096) = stg[r];
    }
    __syncthreads();  // all hk A-reads + Bs writes done before hk overwrite
#pragma unroll
    for (int j = 0; j < 8; ++j) {
      int col = (j >> 2) * 512 + w * 64 + (j & 3) * 16 + lrow;
#pragma unroll
      for (int r = 0; r < 4; ++r) {
        float hv = tanhf(xpr[j][r] + (acc[j][r] + brec[j]) * mod);
        hk[(quad * 4 + r) * 1032 + col] = f2bf(hv);
      }
    }
  }

  // ---- out = h @ Wo^T + b_out ----  (Wo chunk0 already in Bs[0])
  f32x4 a3[2] = {};
#pragma unroll 1
  for (int c = 0; c < 32; ++c) {
    __syncthreads();  // publish Bs[c&1] and (at c=0) the final hk
    if (c < 31) {
      const unsigned short* src = Wo + (size_t)nb * 1024 + (c + 1) * 32 + ko;
#pragma unroll
      for (int r = 0; r < 2; ++r)
        stg[r] = *(const bf16x8*)(src + (size_t)r * 131072);
    }
    bf16x8 a = *(const bf16x8*)&hk[lrow * 1032 + c * 32 + quad * 8];
    const unsigned short* bs = Bs[c & 1];
#pragma unroll
    for (int f = 0; f < 2; ++f) {
      bf16x8 b = *(const bf16x8*)&bs[(w * 32 + f * 16 + lrow) * 32 + quad * 8];
      a3[f] = __builtin_amdgcn_mfma_f32_16x16x32_bf16(a, b, a3[f], 0, 0, 0);
    }
    if (c < 31) {
      unsigned short* dst = &Bs[(c + 1) & 1][tid * 8];
#pragma unroll
      for (int r = 0; r < 2; ++r)
        *(bf16x8*)(dst + r * 4096) = stg[r];
    }
  }
#pragma unroll
  for (int f = 0; f < 2; ++f) {
    int col = w * 32 + f * 16 + lrow;
#pragma unroll
    for (int r = 0; r < 4; ++r)
      out[(size_t)(m0 + quad * 4 + r) * 256 + col] = a3[f][r] + bout[f];
  }
}

extern "C" void kernel_launch(void* const* d_in, const int* in_sizes, int n_in,
                              void* d_out, int out_size, void* d_ws, size_t ws_size,
                              hipStream_t stream) {
  const float* x     = (const float*)d_in[0];
  const float* W_in  = (const float*)d_in[1];
  const float* b_in  = (const float*)d_in[2];
  const float* W_rec = (const float*)d_in[3];
  const float* b_rec = (const float*)d_in[4];
  const float* W_out = (const float*)d_in[5];
  const float* b_out = (const float*)d_in[6];
  const float* u_in  = (const float*)d_in[7];
  const float* u_rec = (const float*)d_in[8];
  const float* u_out = (const float*)d_in[9];

  const int B = 4096, DIN = 1024, H = 1024, DOUT = 256;

  char* w = (char*)d_ws;
  float* S = (float*)w;
  float* v_in = S + 256;
  float* v_rec = v_in + 1024;
  float* v_out = v_rec + 1024;
  unsigned short* Wi_bf = (unsigned short*)(w + (1 << 14));
  unsigned short* Wr_bf = Wi_bf + (size_t)H * DIN;
  unsigned short* Wo_bf = Wr_bf + (size_t)H * H;
  unsigned short* x_bf  = Wo_bf + (size_t)DOUT * H;
  float* xproj = (float*)(x_bf + (size_t)B * DIN);
  unsigned short* hA = (unsigned short*)(xproj + (size_t)B * H);

  hipMemsetAsync(w, 0, 1 << 14, stream);

  dim3 t256(256);
  spec_col_partial<<<dim3(DIN / 256, H / 64), t256, 0, stream>>>(W_in, u_in, v_in, H, DIN, 64);
  spec_col_partial<<<dim3(H / 256, H / 64), t256, 0, stream>>>(W_rec, u_rec, v_rec, H, H, 64);
  spec_col_partial<<<dim3(H / 256, DOUT / 64), t256, 0, stream>>>(W_out, u_out, v_out, DOUT, H, 64);
  vec_norm2<<<1, t256, 0, stream>>>(v_in, &S[0], DIN);
  vec_norm2<<<1, t256, 0, stream>>>(v_rec, &S[1], H);
  vec_norm2<<<1, t256, 0, stream>>>(v_out, &S[2], H);
  spec_row_sq<<<H, t256, 0, stream>>>(W_in, v_in, &S[3], DIN);
  spec_row_sq<<<H, t256, 0, stream>>>(W_rec, v_rec, &S[4], H);
  spec_row_sq<<<DOUT, t256, 0, stream>>>(W_out, v_out, &S[5], H);
  spec_finalize<<<1, 64, 0, stream>>>(S);

  cvt_scaled<<<512, t256, 0, stream>>>((const float4*)W_in, &S[6], (ushort4*)Wi_bf, H * DIN / 4);
  cvt_scaled<<<512, t256, 0, stream>>>((const float4*)W_rec, &S[7], (ushort4*)Wr_bf, H * H / 4);
  cvt_scaled<<<128, t256, 0, stream>>>((const float4*)W_out, &S[8], (ushort4*)Wo_bf, DOUT * H / 4);
  cvt_scaled<<<1024, t256, 0, stream>>>((const float4*)x, &S[9], (ushort4*)x_bf, B * DIN / 4);

  gemm_bt0<<<dim3(B / 128, H / 128), t256, 0, stream>>>(
      x_bf, Wi_bf, b_in, xproj, B, H, DIN);

  step0k<<<2048, t256, 0, stream>>>((const float4*)xproj, (const float4*)b_rec,
                                    (ushort4*)hA, 1.0f, B * H / 4, H / 4 - 1);

  Mods mods;
  for (int t = 0; t < 32; ++t) mods.m[t] = (float)(1.0 + 0.1 * sin(0.3 * (double)t));

  rnn_persist<<<256, 512, 0, stream>>>(hA, xproj, Wr_bf, Wo_bf, b_rec, b_out,
                                       (float*)d_out, mods);
}

// Round 5
// 1101.020 us; speedup vs baseline: 25.4312x; 25.4312x over previous
//
#include <hip/hip_runtime.h>
#include <hip/hip_bf16.h>
#include <math.h>
#include <stdint.h>

// HolomorphicEqProp: B=4096, D_IN=H=1024, D_OUT=256, steps=30.
// Round-5: validated R1 multi-kernel structure, retiled 128x128 -> 64x128
// (grid 256 -> 512 blocks, 1 -> 2 blocks/CU) to attack the R1 occupancy
// bottleneck (R1: 1 wave/SIMD, MfmaUtil 6.5%, 45 us/step).
// NOTE (R2/R3 post-mortem): global_load_lds with runtime-varying LDS dest
// across barriers corrupts data — only the R1 pattern (compile-time dest,
// issue -> barrier -> read) is used here.

#define EPSF 1e-12f

typedef short bf16x8 __attribute__((ext_vector_type(8)));
typedef float f32x4 __attribute__((ext_vector_type(4)));

__device__ __forceinline__ unsigned short f2bf(float f) {
  union { float f; unsigned u; } v; v.f = f;
  unsigned r = v.u + 0x7FFFu + ((v.u >> 16) & 1u);  // RNE
  return (unsigned short)(r >> 16);
}

// async global->LDS, 16B/lane; dest = wave-uniform base + lane*16 (R1 pattern)
__device__ __forceinline__ void async16(const void* g, void* l) {
  __builtin_amdgcn_global_load_lds(
      (__attribute__((address_space(1))) void*)(uintptr_t)(g),
      (__attribute__((address_space(3))) void*)(unsigned)(uintptr_t)(l),
      16, 0, 0);
}

__device__ __forceinline__ float block_reduce_sum(float x) {
#pragma unroll
  for (int o = 32; o > 0; o >>= 1) x += __shfl_down(x, o, 64);
  __shared__ float sm[8];
  int lane = threadIdx.x & 63, w = threadIdx.x >> 6;
  if (lane == 0) sm[w] = x;
  __syncthreads();
  float t = 0.f;
  if (threadIdx.x == 0) {
    int nw = (int)(blockDim.x >> 6);
    for (int i = 0; i < nw; ++i) t += sm[i];
  }
  return t;
}

// ---------------- spectral-norm setup (fp32, exact; validated) ----------

__global__ void spec_col_partial(const float* __restrict__ W, const float* __restrict__ u,
                                 float* __restrict__ v, int M, int N, int rowsPerBlock) {
  int j = blockIdx.x * blockDim.x + threadIdx.x;
  int i0 = blockIdx.y * rowsPerBlock;
  float acc = 0.f;
  for (int i = i0; i < i0 + rowsPerBlock; ++i)
    acc += W[(size_t)i * N + j] * u[i];
  atomicAdd(&v[j], acc);
}

__global__ void vec_norm2(const float* __restrict__ v, float* __restrict__ out, int n) {
  float acc = 0.f;
  for (int i = threadIdx.x; i < n; i += blockDim.x) { float x = v[i]; acc += x * x; }
  float t = block_reduce_sum(acc);
  if (threadIdx.x == 0) *out = t;
}

__global__ void spec_row_sq(const float* __restrict__ W, const float* __restrict__ v,
                            float* __restrict__ usq, int N) {
  int i = blockIdx.x;
  float acc = 0.f;
  for (int j = threadIdx.x; j < N; j += blockDim.x)
    acc += W[(size_t)i * N + j] * v[j];
  float r = block_reduce_sum(acc);
  if (threadIdx.x == 0) atomicAdd(usq, r * r);
}

__global__ void spec_finalize(float* S) {
  int m = threadIdx.x;
  if (m < 3) {
    float nv = sqrtf(S[m]);
    float inv = 1.f / (nv + EPSF);
    float u2sq = S[3 + m] * inv * inv;
    float nu = sqrtf(u2sq);
    float sigma = u2sq / (nu + EPSF);
    S[6 + m] = 1.f / sigma;
  }
  if (m == 3) S[9] = 1.0f;
}

__global__ void cvt_scaled(const float4* __restrict__ W, const float* __restrict__ sp,
                           ushort4* __restrict__ o, int n4) {
  float s = *sp;
  for (int i = blockIdx.x * blockDim.x + threadIdx.x; i < n4; i += gridDim.x * blockDim.x) {
    float4 w = W[i];
    ushort4 r;
    r.x = f2bf(w.x * s); r.y = f2bf(w.y * s); r.z = f2bf(w.z * s); r.w = f2bf(w.w * s);
    o[i] = r;
  }
}

// h1 = tanh(xproj + b_rec*mod0), mod0 = 1  (validated)
__global__ void step0k(const float4* __restrict__ xp, const float4* __restrict__ br,
                       ushort4* __restrict__ h, float mod, int n4, int colmask4) {
  for (int i = blockIdx.x * blockDim.x + threadIdx.x; i < n4; i += gridDim.x * blockDim.x) {
    float4 x = xp[i];
    float4 b = br[i & colmask4];
    ushort4 r;
    r.x = f2bf(tanhf(x.x + b.x * mod));
    r.y = f2bf(tanhf(x.y + b.y * mod));
    r.z = f2bf(tanhf(x.z + b.z * mod));
    r.w = f2bf(tanhf(x.w + b.w * mod));
    h[i] = r;
  }
}

// C = A[M,K] . B[N,K]^T, bf16 in / fp32 accum. 64x128 tile, BK=32,
// 4 waves 2x2 (each 32x64 = 2x4 frags of 16x16x32).
// MODE 0: outF = acc + bias[n]
// MODE 1: outBf = bf16(tanh(xproj + (acc + bias[n])*mod))
template <int MODE>
__global__ __launch_bounds__(256) void gemm_bt(
    const unsigned short* __restrict__ A, const unsigned short* __restrict__ B,
    const float* __restrict__ bias, const float* __restrict__ xproj, float mod,
    float* __restrict__ outF, unsigned short* __restrict__ outBf,
    int M, int N, int K) {
  constexpr int BM = 64, BN = 128, BK = 32;
  __shared__ __align__(16) unsigned short As[BM * BK];
  __shared__ __align__(16) unsigned short Bs[BN * BK];
  const int tid = threadIdx.x;
  const int wave = tid >> 6, lane = tid & 63;
  const int m0 = blockIdx.x * BM, n0 = blockIdx.y * BN;
  const int wm = (wave >> 1) * 32, wn = (wave & 1) * 64;
  const int lrow = lane & 15, quad = lane >> 4;

  f32x4 acc[2][4] = {};

  for (int k0 = 0; k0 < K; k0 += BK) {
    {
      int e = tid * 8;                     // A tile: 64x32 = 2048 elems
      int r = e >> 5, c = e & 31;
      async16(&A[(size_t)(m0 + r) * K + k0 + c], &As[e]);
#pragma unroll
      for (int inst = 0; inst < 2; ++inst) {  // B tile: 128x32 = 4096 elems
        int eb = inst * 2048 + tid * 8;
        int rb = eb >> 5, cb = eb & 31;
        async16(&B[(size_t)(n0 + rb) * K + k0 + cb], &Bs[eb]);
      }
    }
    __syncthreads();  // drains vmcnt(0) for the LDS-DMA + barrier

    bf16x8 af[2], bfr[4];
#pragma unroll
    for (int i = 0; i < 2; ++i)
      af[i] = *(const bf16x8*)&As[(wm + i * 16 + lrow) * BK + quad * 8];
#pragma unroll
    for (int j = 0; j < 4; ++j)
      bfr[j] = *(const bf16x8*)&Bs[(wn + j * 16 + lrow) * BK + quad * 8];
#pragma unroll
    for (int i = 0; i < 2; ++i)
#pragma unroll
      for (int j = 0; j < 4; ++j)
        acc[i][j] = __builtin_amdgcn_mfma_f32_16x16x32_bf16(af[i], bfr[j], acc[i][j], 0, 0, 0);
    __syncthreads();
  }

#pragma unroll
  for (int i = 0; i < 2; ++i) {
#pragma unroll
    for (int j = 0; j < 4; ++j) {
      int col = n0 + wn + j * 16 + lrow;
      float bv = bias[col];
#pragma unroll
      for (int r = 0; r < 4; ++r) {
        int row = m0 + wm + i * 16 + quad * 4 + r;
        size_t idx = (size_t)row * N + col;
        float val = acc[i][j][r] + bv;
        if (MODE == 1) {
          outBf[idx] = f2bf(tanhf(xproj[idx] + val * mod));
        } else {
          outF[idx] = val;
        }
      }
    }
  }
}

extern "C" void kernel_launch(void* const* d_in, const int* in_sizes, int n_in,
                              void* d_out, int out_size, void* d_ws, size_t ws_size,
                              hipStream_t stream) {
  const float* x     = (const float*)d_in[0];
  const float* W_in  = (const float*)d_in[1];
  const float* b_in  = (const float*)d_in[2];
  const float* W_rec = (const float*)d_in[3];
  const float* b_rec = (const float*)d_in[4];
  const float* W_out = (const float*)d_in[5];
  const float* b_out = (const float*)d_in[6];
  const float* u_in  = (const float*)d_in[7];
  const float* u_rec = (const float*)d_in[8];
  const float* u_out = (const float*)d_in[9];

  const int B = 4096, DIN = 1024, H = 1024, DOUT = 256, STEPS = 30;

  char* w = (char*)d_ws;
  float* S = (float*)w;
  float* v_in = S + 256;
  float* v_rec = v_in + 1024;
  float* v_out = v_rec + 1024;
  unsigned short* Wi_bf = (unsigned short*)(w + (1 << 14));
  unsigned short* Wr_bf = Wi_bf + (size_t)H * DIN;
  unsigned short* Wo_bf = Wr_bf + (size_t)H * H;
  unsigned short* x_bf  = Wo_bf + (size_t)DOUT * H;
  float* xproj = (float*)(x_bf + (size_t)B * DIN);
  unsigned short* hA = (unsigned short*)(xproj + (size_t)B * H);
  unsigned short* hB = hA + (size_t)B * H;

  hipMemsetAsync(w, 0, 1 << 14, stream);

  dim3 t256(256);
  spec_col_partial<<<dim3(DIN / 256, H / 64), t256, 0, stream>>>(W_in, u_in, v_in, H, DIN, 64);
  spec_col_partial<<<dim3(H / 256, H / 64), t256, 0, stream>>>(W_rec, u_rec, v_rec, H, H, 64);
  spec_col_partial<<<dim3(H / 256, DOUT / 64), t256, 0, stream>>>(W_out, u_out, v_out, DOUT, H, 64);
  vec_norm2<<<1, t256, 0, stream>>>(v_in, &S[0], DIN);
  vec_norm2<<<1, t256, 0, stream>>>(v_rec, &S[1], H);
  vec_norm2<<<1, t256, 0, stream>>>(v_out, &S[2], H);
  spec_row_sq<<<H, t256, 0, stream>>>(W_in, v_in, &S[3], DIN);
  spec_row_sq<<<H, t256, 0, stream>>>(W_rec, v_rec, &S[4], H);
  spec_row_sq<<<DOUT, t256, 0, stream>>>(W_out, v_out, &S[5], H);
  spec_finalize<<<1, 64, 0, stream>>>(S);

  cvt_scaled<<<512, t256, 0, stream>>>((const float4*)W_in, &S[6], (ushort4*)Wi_bf, H * DIN / 4);
  cvt_scaled<<<512, t256, 0, stream>>>((const float4*)W_rec, &S[7], (ushort4*)Wr_bf, H * H / 4);
  cvt_scaled<<<128, t256, 0, stream>>>((const float4*)W_out, &S[8], (ushort4*)Wo_bf, DOUT * H / 4);
  cvt_scaled<<<1024, t256, 0, stream>>>((const float4*)x, &S[9], (ushort4*)x_bf, B * DIN / 4);

  // xproj = x @ Wi_n^T + b_in (fp32)
  gemm_bt<0><<<dim3(B / 64, H / 128), t256, 0, stream>>>(
      x_bf, Wi_bf, b_in, nullptr, 0.f, xproj, nullptr, B, H, DIN);

  // t=0 (h=0): h = tanh(xproj + b_rec), mod0 = 1
  step0k<<<2048, t256, 0, stream>>>((const float4*)xproj, (const float4*)b_rec,
                                    (ushort4*)hA, 1.0f, B * H / 4, H / 4 - 1);

  // steps t = 1..29: h = tanh(xproj + (h @ Wr_n^T + b_rec) * mod(t))
  unsigned short* cur = hA;
  unsigned short* nxt = hB;
  for (int t = 1; t < STEPS; ++t) {
    float mod = 1.0f + 0.1f * (float)sin(0.3 * (double)t);
    gemm_bt<1><<<dim3(B / 64, H / 128), t256, 0, stream>>>(
        cur, Wr_bf, b_rec, xproj, mod, nullptr, nxt, B, H, H);
    unsigned short* tmp = cur; cur = nxt; nxt = tmp;
  }

  // out = h @ Wo_n^T + b_out
  gemm_bt<0><<<dim3(B / 64, DOUT / 128), t256, 0, stream>>>(
      cur, Wo_bf, b_out, nullptr, 0.f, (float*)d_out, nullptr, B, DOUT, H);
}